// Round 1
// baseline (146.872 us; speedup 1.0000x reference)
//
#include <hip/hip_runtime.h>

#define NPTS 4096
#define BATCH 8
#define BLK 256

// ---------------------------------------------------------------------------
// Kernel 1: for each point in one set, min squared distance to all points of
// the other set. grid = (NPTS/BLK, BATCH, 2). dir=0: for each x, min over y.
// dir=1: for each y, min over x. Output layout: [dir][b][n].
// ---------------------------------------------------------------------------
__global__ __launch_bounds__(BLK) void dmin_kernel(
    const float* __restrict__ X, const float* __restrict__ Y,
    float* __restrict__ out) {
  const int b   = blockIdx.y;
  const int dir = blockIdx.z;
  const float* pts = dir ? Y : X;  // set we compute mins for
  const float* oth = dir ? X : Y;  // set we min over

  __shared__ float s[3 * NPTS];  // 48 KB
  const float* othb = oth + (size_t)b * NPTS * 3;
  for (int i = threadIdx.x; i < 3 * NPTS / 4; i += BLK) {
    ((float4*)s)[i] = ((const float4*)othb)[i];
  }
  __syncthreads();

  const int n = blockIdx.x * BLK + threadIdx.x;
  const float* p = pts + ((size_t)b * NPTS + n) * 3;
  const float px = p[0], py = p[1], pz = p[2];

  // 4 independent accumulators to break the fminf dependency chain.
  float b0 = 3.4e38f, b1 = 3.4e38f, b2 = 3.4e38f, b3 = 3.4e38f;
  for (int m = 0; m < NPTS; m += 4) {
    const float* q = &s[3 * m];  // 12 consecutive floats -> 3x ds_read_b128
    float dx0 = px - q[0],  dy0 = py - q[1],  dz0 = pz - q[2];
    float dx1 = px - q[3],  dy1 = py - q[4],  dz1 = pz - q[5];
    float dx2 = px - q[6],  dy2 = py - q[7],  dz2 = pz - q[8];
    float dx3 = px - q[9],  dy3 = py - q[10], dz3 = pz - q[11];
    float d0 = dx0 * dx0 + dy0 * dy0 + dz0 * dz0;
    float d1 = dx1 * dx1 + dy1 * dy1 + dz1 * dz1;
    float d2 = dx2 * dx2 + dy2 * dy2 + dz2 * dz2;
    float d3 = dx3 * dx3 + dy3 * dy3 + dz3 * dz3;
    b0 = fminf(b0, d0);
    b1 = fminf(b1, d1);
    b2 = fminf(b2, d2);
    b3 = fminf(b3, d3);
  }
  float best = fminf(fminf(b0, b1), fminf(b2, b3));
  out[(size_t)dir * BATCH * NPTS + (size_t)b * NPTS + n] = best;
}

// ---------------------------------------------------------------------------
// Block-wide sum reduction (1024 threads = 16 waves), result broadcast to all.
// ---------------------------------------------------------------------------
__device__ float block_reduce_sum(float val) {
  __shared__ float tmp[16];
  for (int off = 32; off > 0; off >>= 1) val += __shfl_down(val, off, 64);
  const int wid  = threadIdx.x >> 6;
  const int lane = threadIdx.x & 63;
  if (lane == 0) tmp[wid] = val;
  __syncthreads();
  float r = (lane < 16) ? tmp[lane] : 0.0f;
  for (int off = 8; off > 0; off >>= 1) r += __shfl_down(r, off, 64);
  r = __shfl(r, 0, 64);  // broadcast within each wave
  __syncthreads();       // protect tmp for next call
  return r;
}

// ---------------------------------------------------------------------------
// Kernel 2: per (dir,b) vector of 4096 min-distances, compute the reference's
// masked mean: mean, std(ddof=1), keep v where (v-mean) > -0.5*std, mean of
// kept. Sum the two directions per batch, then mean over batch -> scalar.
// Single block, fully deterministic.
// ---------------------------------------------------------------------------
__global__ __launch_bounds__(1024) void finalize_kernel(
    const float* __restrict__ dmin, float* __restrict__ out) {
  float total = 0.0f;
  for (int b = 0; b < BATCH; ++b) {
    for (int dir = 0; dir < 2; ++dir) {
      const float* v = dmin + ((size_t)dir * BATCH + b) * NPTS;

      // pass 1: mean
      float sum = 0.0f;
      for (int i = threadIdx.x; i < NPTS; i += 1024) sum += v[i];
      sum = block_reduce_sum(sum);
      const float mean = sum / (float)NPTS;

      // pass 2: unbiased std
      float ss = 0.0f;
      for (int i = threadIdx.x; i < NPTS; i += 1024) {
        float d = v[i] - mean;
        ss += d * d;
      }
      ss = block_reduce_sum(ss);
      const float stdv = sqrtf(ss / (float)(NPTS - 1));

      // pass 3: masked sum + count, strict '>' as in reference
      float ksum = 0.0f, kcnt = 0.0f;
      const float neg_thr = -0.5f * stdv;
      for (int i = threadIdx.x; i < NPTS; i += 1024) {
        float val = v[i];
        if (val - mean > neg_thr) {
          ksum += val;
          kcnt += 1.0f;
        }
      }
      ksum = block_reduce_sum(ksum);
      kcnt = block_reduce_sum(kcnt);
      total += ksum / kcnt;
    }
  }
  if (threadIdx.x == 0) out[0] = total / (float)BATCH;
}

extern "C" void kernel_launch(void* const* d_in, const int* in_sizes, int n_in,
                              void* d_out, int out_size, void* d_ws, size_t ws_size,
                              hipStream_t stream) {
  const float* x = (const float*)d_in[0];
  const float* y = (const float*)d_in[1];
  float* out  = (float*)d_out;
  float* dmin = (float*)d_ws;  // needs 2*8*4096*4 = 256 KB

  dim3 g1(NPTS / BLK, BATCH, 2);
  dmin_kernel<<<g1, BLK, 0, stream>>>(x, y, dmin);
  finalize_kernel<<<1, 1024, 0, stream>>>(dmin, out);
}

// Round 2
// 46.743 us; speedup vs baseline: 3.1421x; 3.1421x over previous
//
#include <hip/hip_runtime.h>

#define NPTS 4096
#define BATCH 8
#define BLK 256
#define PPT 2                       // p-points per thread
#define MCH 512                     // q-chunk staged in LDS
#define NCHUNK (NPTS / MCH)         // 8
#define NPB (BLK * PPT)             // 512 p-points per block

// ---------------------------------------------------------------------------
// Init: fill dmin (as uint) with +huge float bits. 2*8*4096 = 65536 uints.
// ---------------------------------------------------------------------------
__global__ __launch_bounds__(256) void init_kernel(uint4* __restrict__ p) {
  // 65536 uints = 16384 uint4; grid 64 x 256 threads
  const unsigned v = 0x7f7f7f7fu;  // 3.39e38f
  p[blockIdx.x * 256 + threadIdx.x] = make_uint4(v, v, v, v);
}

// ---------------------------------------------------------------------------
// Kernel 1: partial min over one q-chunk, combined across chunks by atomicMin
// on float-as-uint (values >= ~0, so uint order == float order; rare ~1e-7
// negative cancellation values lose the min by <=2e-7 -- far below threshold).
// grid = (NPTS/NPB=8, BATCH=8, 2*NCHUNK=16), z = dir*NCHUNK + chunk.
// d2 = |p|^2 + |q|^2 - 2 p.q  (same expansion as the reference), with
// LDS staging of (-2qx, -2qy, -2qz, |q|^2) so d = fma chain of 4 ops.
// ---------------------------------------------------------------------------
__global__ __launch_bounds__(BLK) void dmin_kernel(
    const float* __restrict__ X, const float* __restrict__ Y,
    unsigned int* __restrict__ dmin) {
  const int b     = blockIdx.y;
  const int dir   = blockIdx.z >> 3;
  const int chunk = blockIdx.z & (NCHUNK - 1);
  const float* pts = dir ? Y : X;  // set we compute mins for
  const float* oth = dir ? X : Y;  // set we min over

  __shared__ float4 s[MCH];  // 8 KB
  const float* othb = oth + ((size_t)b * NPTS + (size_t)chunk * MCH) * 3;
  for (int i = threadIdx.x; i < MCH; i += BLK) {
    float qx = othb[3 * i], qy = othb[3 * i + 1], qz = othb[3 * i + 2];
    s[i] = make_float4(-2.f * qx, -2.f * qy, -2.f * qz,
                       qx * qx + qy * qy + qz * qz);
  }
  __syncthreads();

  const int n0 = blockIdx.x * NPB + threadIdx.x;
  const int n1 = n0 + BLK;
  const float* p0p = pts + ((size_t)b * NPTS + n0) * 3;
  const float* p1p = pts + ((size_t)b * NPTS + n1) * 3;
  const float p0x = p0p[0], p0y = p0p[1], p0z = p0p[2];
  const float p1x = p1p[0], p1y = p1p[1], p1z = p1p[2];
  const float c0 = p0x * p0x + p0y * p0y + p0z * p0z;
  const float c1 = p1x * p1x + p1y * p1y + p1z * p1z;

  float a0 = 3.4e38f, a1 = 3.4e38f;  // two accumulators for p0
  float a2 = 3.4e38f, a3 = 3.4e38f;  // two for p1
  for (int m = 0; m < MCH; m += 4) {
    float4 q0 = s[m], q1 = s[m + 1], q2 = s[m + 2], q3 = s[m + 3];
    float d00 = fmaf(p0x, q0.x, fmaf(p0y, q0.y, fmaf(p0z, q0.z, c0 + q0.w)));
    float d01 = fmaf(p0x, q1.x, fmaf(p0y, q1.y, fmaf(p0z, q1.z, c0 + q1.w)));
    float d02 = fmaf(p0x, q2.x, fmaf(p0y, q2.y, fmaf(p0z, q2.z, c0 + q2.w)));
    float d03 = fmaf(p0x, q3.x, fmaf(p0y, q3.y, fmaf(p0z, q3.z, c0 + q3.w)));
    float d10 = fmaf(p1x, q0.x, fmaf(p1y, q0.y, fmaf(p1z, q0.z, c1 + q0.w)));
    float d11 = fmaf(p1x, q1.x, fmaf(p1y, q1.y, fmaf(p1z, q1.z, c1 + q1.w)));
    float d12 = fmaf(p1x, q2.x, fmaf(p1y, q2.y, fmaf(p1z, q2.z, c1 + q2.w)));
    float d13 = fmaf(p1x, q3.x, fmaf(p1y, q3.y, fmaf(p1z, q3.z, c1 + q3.w)));
    a0 = fminf(fminf(a0, d00), d01);   // -> v_min3
    a1 = fminf(fminf(a1, d02), d03);
    a2 = fminf(fminf(a2, d10), d11);
    a3 = fminf(fminf(a3, d12), d13);
  }
  const size_t base = (size_t)dir * BATCH * NPTS + (size_t)b * NPTS;
  atomicMin(&dmin[base + n0], __float_as_uint(fminf(a0, a1)));
  atomicMin(&dmin[base + n1], __float_as_uint(fminf(a2, a3)));
}

// ---------------------------------------------------------------------------
// Kernel 2: 16 waves, wave w handles (dir,b)=w: masked mean per the reference
// (mean, ddof=1 std, strict (v-mean) > -0.5*std, mean of kept). Shuffle-only
// wave reductions, deterministic ordered final combine.
// ---------------------------------------------------------------------------
__global__ __launch_bounds__(1024) void finalize_kernel(
    const float* __restrict__ dmin, float* __restrict__ out) {
  const int w    = threadIdx.x >> 6;   // 0..15 = dir*8+b
  const int lane = threadIdx.x & 63;
  const float4* v = (const float4*)(dmin + (size_t)w * NPTS);

  // pass 1: mean
  float sum = 0.0f;
  for (int i = lane; i < NPTS / 4; i += 64) {
    float4 t = v[i];
    sum += (t.x + t.y) + (t.z + t.w);
  }
  for (int off = 32; off; off >>= 1) sum += __shfl_xor(sum, off, 64);
  const float mean = sum / (float)NPTS;

  // pass 2: unbiased std
  float ss = 0.0f;
  for (int i = lane; i < NPTS / 4; i += 64) {
    float4 t = v[i];
    float d0 = t.x - mean, d1 = t.y - mean, d2 = t.z - mean, d3 = t.w - mean;
    ss += (d0 * d0 + d1 * d1) + (d2 * d2 + d3 * d3);
  }
  for (int off = 32; off; off >>= 1) ss += __shfl_xor(ss, off, 64);
  const float stdv = sqrtf(ss / (float)(NPTS - 1));
  const float neg_thr = -0.5f * stdv;

  // pass 3: masked sum + count (strict '>')
  float ksum = 0.0f, kcnt = 0.0f;
  for (int i = lane; i < NPTS / 4; i += 64) {
    float4 t = v[i];
    if (t.x - mean > neg_thr) { ksum += t.x; kcnt += 1.0f; }
    if (t.y - mean > neg_thr) { ksum += t.y; kcnt += 1.0f; }
    if (t.z - mean > neg_thr) { ksum += t.z; kcnt += 1.0f; }
    if (t.w - mean > neg_thr) { ksum += t.w; kcnt += 1.0f; }
  }
  for (int off = 32; off; off >>= 1) ksum += __shfl_xor(ksum, off, 64);
  for (int off = 32; off; off >>= 1) kcnt += __shfl_xor(kcnt, off, 64);

  __shared__ float res[16];
  if (lane == 0) res[w] = ksum / kcnt;
  __syncthreads();
  if (threadIdx.x == 0) {
    float tot = 0.0f;
    for (int i = 0; i < 16; ++i) tot += res[i];  // fixed order: deterministic
    out[0] = tot / (float)BATCH;
  }
}

extern "C" void kernel_launch(void* const* d_in, const int* in_sizes, int n_in,
                              void* d_out, int out_size, void* d_ws, size_t ws_size,
                              hipStream_t stream) {
  const float* x = (const float*)d_in[0];
  const float* y = (const float*)d_in[1];
  float* out = (float*)d_out;
  unsigned int* dmin = (unsigned int*)d_ws;  // 2*8*4096*4 = 256 KB

  init_kernel<<<64, 256, 0, stream>>>((uint4*)d_ws);
  dim3 g1(NPTS / NPB, BATCH, 2 * NCHUNK);
  dmin_kernel<<<g1, BLK, 0, stream>>>(x, y, dmin);
  finalize_kernel<<<1, 1024, 0, stream>>>((const float*)dmin, out);
}

// Round 5
// 45.738 us; speedup vs baseline: 3.2111x; 1.0220x over previous
//
#include <hip/hip_runtime.h>

#define NPTS 4096
#define BATCH 8
#define BLK 256
#define PPT 4                        // p-points per thread
#define NPB (BLK * PPT)              // 1024 p-points per block
#define MCH 512                      // q-points staged in LDS per block
#define NCHUNK (NPTS / MCH)          // 8

// ---------------------------------------------------------------------------
// Kernel 1: partial min over one q-chunk. grid = (4, 8, 16), z = dir*8+chunk.
// LDS holds (-2qx,-2qy,-2qz,|q|^2); |p|^2 is folded OUT of the inner loop:
// d' = |q|^2 - 2 p.q  (3 FMA), final = min(d') + |p|^2.
// Output: partial[chunk][dir][b][n], written as float4 (no atomics, no init).
// ---------------------------------------------------------------------------
__global__ __launch_bounds__(BLK) void dmin_kernel(
    const float* __restrict__ X, const float* __restrict__ Y,
    float* __restrict__ partial) {
  const int b     = blockIdx.y;
  const int dir   = blockIdx.z >> 3;
  const int chunk = blockIdx.z & (NCHUNK - 1);
  const float* pts = dir ? Y : X;  // set we compute mins for
  const float* oth = dir ? X : Y;  // set we min over

  __shared__ float4 s[MCH];  // 8 KB
  const float* othb = oth + ((size_t)b * NPTS + (size_t)chunk * MCH) * 3;
  for (int i = threadIdx.x; i < MCH; i += BLK) {
    float qx = othb[3 * i], qy = othb[3 * i + 1], qz = othb[3 * i + 2];
    s[i] = make_float4(-2.f * qx, -2.f * qy, -2.f * qz,
                       qx * qx + qy * qy + qz * qz);
  }
  __syncthreads();

  const int n0 = blockIdx.x * NPB + threadIdx.x * PPT;  // 4 consecutive points
  const float* p = pts + ((size_t)b * NPTS + n0) * 3;
  const float p0x = p[0], p0y = p[1],  p0z = p[2];
  const float p1x = p[3], p1y = p[4],  p1z = p[5];
  const float p2x = p[6], p2y = p[7],  p2z = p[8];
  const float p3x = p[9], p3y = p[10], p3z = p[11];

#define DQ(P) fmaf(p##P##x, q.x, fmaf(p##P##y, q.y, fmaf(p##P##z, q.z, q.w)))
  float a0 = 3.4e38f, a1 = 3.4e38f, a2 = 3.4e38f, a3 = 3.4e38f;
  float a4 = 3.4e38f, a5 = 3.4e38f, a6 = 3.4e38f, a7 = 3.4e38f;
#pragma unroll 2
  for (int m = 0; m < MCH; m += 4) {
    float4 q;
    q = s[m + 0];
    float d00 = DQ(0), d10 = DQ(1), d20 = DQ(2), d30 = DQ(3);
    q = s[m + 1];
    float d01 = DQ(0), d11 = DQ(1), d21 = DQ(2), d31 = DQ(3);
    q = s[m + 2];
    float d02 = DQ(0), d12 = DQ(1), d22 = DQ(2), d32 = DQ(3);
    q = s[m + 3];
    float d03 = DQ(0), d13 = DQ(1), d23 = DQ(2), d33 = DQ(3);
    a0 = fminf(fminf(a0, d00), d01);  // -> v_min3
    a1 = fminf(fminf(a1, d02), d03);
    a2 = fminf(fminf(a2, d10), d11);
    a3 = fminf(fminf(a3, d12), d13);
    a4 = fminf(fminf(a4, d20), d21);
    a5 = fminf(fminf(a5, d22), d23);
    a6 = fminf(fminf(a6, d30), d31);
    a7 = fminf(fminf(a7, d32), d33);
  }
#undef DQ
  const float c0 = p0x * p0x + p0y * p0y + p0z * p0z;
  const float c1 = p1x * p1x + p1y * p1y + p1z * p1z;
  const float c2 = p2x * p2x + p2y * p2y + p2z * p2z;
  const float c3 = p3x * p3x + p3y * p3y + p3z * p3z;
  float4 r;
  r.x = fminf(a0, a1) + c0;
  r.y = fminf(a2, a3) + c1;
  r.z = fminf(a4, a5) + c2;
  r.w = fminf(a6, a7) + c3;
  *(float4*)&partial[(((size_t)chunk * 2 + dir) * BATCH + b) * NPTS + n0] = r;
}

// ---------------------------------------------------------------------------
// Kernel 2: grid = 2 blocks (one per dir), 512 threads = 8 waves, wave = one
// batch b. Pass A: 8-way chunk-min fused with sum & sumsq (one-pass var,
// ddof=1), minned vector parked in LDS. Pass B: strict mask (v-mean > -0.5*std)
// sum+count from LDS. Per-block ordered combine, then ONE atomicAdd per block
// (2-way float add is commutative-exact -> bit-deterministic).
// ---------------------------------------------------------------------------
__global__ __launch_bounds__(512) void finalize_kernel(
    const float* __restrict__ partial, float* __restrict__ out) {
  const int dir  = blockIdx.x;
  const int w    = threadIdx.x >> 6;  // batch b
  const int lane = threadIdx.x & 63;

  __shared__ float smin[BATCH][NPTS];  // 128 KB
  __shared__ float res[BATCH];

  const float4* pv = (const float4*)partial;
  const size_t vbase = ((size_t)dir * BATCH + w) * (NPTS / 4);
  const size_t cstr  = (size_t)2 * BATCH * (NPTS / 4);

  float sum = 0.0f, ssq = 0.0f;
  for (int i = lane; i < NPTS / 4; i += 64) {
    float4 m = pv[vbase + i];
#pragma unroll
    for (int c = 1; c < NCHUNK; ++c) {
      float4 t = pv[vbase + (size_t)c * cstr + i];
      m.x = fminf(m.x, t.x); m.y = fminf(m.y, t.y);
      m.z = fminf(m.z, t.z); m.w = fminf(m.w, t.w);
    }
    ((float4*)smin[w])[i] = m;
    sum += (m.x + m.y) + (m.z + m.w);
    ssq += (m.x * m.x + m.y * m.y) + (m.z * m.z + m.w * m.w);
  }
  for (int off = 32; off; off >>= 1) sum += __shfl_xor(sum, off, 64);
  for (int off = 32; off; off >>= 1) ssq += __shfl_xor(ssq, off, 64);
  const float mean = sum / (float)NPTS;
  const float var  = (ssq - (float)NPTS * mean * mean) / (float)(NPTS - 1);
  const float neg_thr = -0.5f * sqrtf(fmaxf(var, 0.0f));

  __syncthreads();  // smin[w] written by this wave only, but keep LDS ordered

  float ksum = 0.0f, kcnt = 0.0f;
  for (int i = lane; i < NPTS / 4; i += 64) {
    float4 t = ((float4*)smin[w])[i];
    if (t.x - mean > neg_thr) { ksum += t.x; kcnt += 1.0f; }
    if (t.y - mean > neg_thr) { ksum += t.y; kcnt += 1.0f; }
    if (t.z - mean > neg_thr) { ksum += t.z; kcnt += 1.0f; }
    if (t.w - mean > neg_thr) { ksum += t.w; kcnt += 1.0f; }
  }
  for (int off = 32; off; off >>= 1) ksum += __shfl_xor(ksum, off, 64);
  for (int off = 32; off; off >>= 1) kcnt += __shfl_xor(kcnt, off, 64);
  if (lane == 0) res[w] = ksum / kcnt;
  __syncthreads();
  if (threadIdx.x == 0) {
    float tot = 0.0f;
    for (int i = 0; i < BATCH; ++i) tot += res[i];  // fixed order
    atomicAdd(out, tot / (float)BATCH);  // 2 blocks: commutative-exact
  }
}

extern "C" void kernel_launch(void* const* d_in, const int* in_sizes, int n_in,
                              void* d_out, int out_size, void* d_ws, size_t ws_size,
                              hipStream_t stream) {
  const float* x = (const float*)d_in[0];
  const float* y = (const float*)d_in[1];
  float* out = (float*)d_out;
  float* partial = (float*)d_ws;  // NCHUNK * 2 * 8 * 4096 * 4B = 2 MB

  hipMemsetAsync(out, 0, sizeof(float), stream);
  dim3 g1(NPTS / NPB, BATCH, 2 * NCHUNK);
  dmin_kernel<<<g1, BLK, 0, stream>>>(x, y, partial);
  finalize_kernel<<<2, 512, 0, stream>>>(partial, out);
}

// Round 8
// 33.968 us; speedup vs baseline: 4.3239x; 1.3465x over previous
//
#include <hip/hip_runtime.h>

#define NPTS 4096
#define BATCH 8
#define BLK 256
#define PPT 4                        // p-points per thread
#define NPB (BLK * PPT)              // 1024 p-points per block
#define MCH 256                      // q-points staged in LDS per block
#define NCHUNK (NPTS / MCH)          // 16
#define PGRP (NPTS / NPB)            // 4

// ---------------------------------------------------------------------------
// Kernel 1: partial min over one q-chunk. grid = (4, 8, 32) = 1024 blocks.
// LDS holds (-2qx,-2qy,-2qz,|q|^2); |p|^2 folded out: d' = |q|^2 - 2 p.q
// (3 FMA/pair), final = min(d') + |p|^2. Also zeroes the finalize ticket
// (stream order: this dispatch fully precedes dispatch 2).
// ---------------------------------------------------------------------------
__global__ __launch_bounds__(BLK, 4) void dmin_kernel(
    const float* __restrict__ X, const float* __restrict__ Y,
    float* __restrict__ partial, unsigned int* __restrict__ ticket) {
  if (blockIdx.x == 0 && blockIdx.y == 0 && blockIdx.z == 0 &&
      threadIdx.x == 0) {
    __hip_atomic_store(ticket, 0u, __ATOMIC_RELAXED, __HIP_MEMORY_SCOPE_AGENT);
  }

  const int pg    = blockIdx.x;
  const int b     = blockIdx.y;
  const int chunk = blockIdx.z & (NCHUNK - 1);
  const int dir   = blockIdx.z >> 4;
  const float* pts = dir ? Y : X;  // set we compute mins for
  const float* oth = dir ? X : Y;  // set we min over

  __shared__ float4 s[MCH];  // 4 KB
  const float* othb = oth + ((size_t)b * NPTS + (size_t)chunk * MCH) * 3;
  {
    const int i = threadIdx.x;  // MCH == BLK: one q per thread
    float qx = othb[3 * i], qy = othb[3 * i + 1], qz = othb[3 * i + 2];
    s[i] = make_float4(-2.f * qx, -2.f * qy, -2.f * qz,
                       qx * qx + qy * qy + qz * qz);
  }
  __syncthreads();

  const int n0 = pg * NPB + threadIdx.x * PPT;  // 4 consecutive p-points
  const float* p = pts + ((size_t)b * NPTS + n0) * 3;
  const float p0x = p[0], p0y = p[1],  p0z = p[2];
  const float p1x = p[3], p1y = p[4],  p1z = p[5];
  const float p2x = p[6], p2y = p[7],  p2z = p[8];
  const float p3x = p[9], p3y = p[10], p3z = p[11];

#define DQ(P) fmaf(p##P##x, q.x, fmaf(p##P##y, q.y, fmaf(p##P##z, q.z, q.w)))
  float a0 = 3.4e38f, a1 = 3.4e38f, a2 = 3.4e38f, a3 = 3.4e38f;
  float a4 = 3.4e38f, a5 = 3.4e38f, a6 = 3.4e38f, a7 = 3.4e38f;
#pragma unroll 2
  for (int m = 0; m < MCH; m += 4) {
    float4 q;
    q = s[m + 0];
    float d00 = DQ(0), d10 = DQ(1), d20 = DQ(2), d30 = DQ(3);
    q = s[m + 1];
    float d01 = DQ(0), d11 = DQ(1), d21 = DQ(2), d31 = DQ(3);
    q = s[m + 2];
    float d02 = DQ(0), d12 = DQ(1), d22 = DQ(2), d32 = DQ(3);
    q = s[m + 3];
    float d03 = DQ(0), d13 = DQ(1), d23 = DQ(2), d33 = DQ(3);
    a0 = fminf(fminf(a0, d00), d01);  // -> v_min3
    a1 = fminf(fminf(a1, d02), d03);
    a2 = fminf(fminf(a2, d10), d11);
    a3 = fminf(fminf(a3, d12), d13);
    a4 = fminf(fminf(a4, d20), d21);
    a5 = fminf(fminf(a5, d22), d23);
    a6 = fminf(fminf(a6, d30), d31);
    a7 = fminf(fminf(a7, d32), d33);
  }
#undef DQ
  const float c0 = p0x * p0x + p0y * p0y + p0z * p0z;
  const float c1 = p1x * p1x + p1y * p1y + p1z * p1z;
  const float c2 = p2x * p2x + p2y * p2y + p2z * p2z;
  const float c3 = p3x * p3x + p3y * p3y + p3z * p3z;
  float4 r;
  r.x = fminf(a0, a1) + c0;
  r.y = fminf(a2, a3) + c1;
  r.z = fminf(a4, a5) + c2;
  r.w = fminf(a6, a7) + c3;
  *(float4*)&partial[(((size_t)chunk * 2 + dir) * BATCH + b) * NPTS + n0] = r;
}

// ---------------------------------------------------------------------------
// Kernel 2: 16 blocks, block w = (dir,b). 16-way chunk-min in registers,
// fused sum/ssq (one-pass ddof=1 var), strict mask (v-mean > -0.5*std),
// fixed-order reductions -> res[w] (agent-scope store). Last block (ticket)
// sums res[0..15] in fixed index order -> out[0]. No memset, no spin-wait,
// bit-deterministic.
// ---------------------------------------------------------------------------
__global__ __launch_bounds__(BLK) void finalize_kernel(
    const float* __restrict__ partial, float* __restrict__ res,
    unsigned int* __restrict__ ticket, float* __restrict__ out) {
  const int w    = blockIdx.x;   // dir*8 + b
  const int dir  = w >> 3;
  const int b    = w & 7;
  const int wid  = threadIdx.x >> 6;
  const int lane = threadIdx.x & 63;

  __shared__ float rA[4], rB[4], rC[4], rD[4];

  const float4* pv = (const float4*)partial;
  const size_t vbase = ((size_t)dir * BATCH + b) * (NPTS / 4);
  const size_t cstr  = (size_t)2 * BATCH * (NPTS / 4);

  float4 mreg[PGRP];  // this thread's 4 minned float4s, kept in registers
  float sum = 0.0f, ssq = 0.0f;
#pragma unroll
  for (int k = 0; k < PGRP; ++k) {
    const int i = threadIdx.x + k * BLK;
    float4 m = pv[vbase + i];
#pragma unroll
    for (int c = 1; c < NCHUNK; ++c) {
      float4 t = pv[vbase + (size_t)c * cstr + i];
      m.x = fminf(m.x, t.x); m.y = fminf(m.y, t.y);
      m.z = fminf(m.z, t.z); m.w = fminf(m.w, t.w);
    }
    mreg[k] = m;
    sum += (m.x + m.y) + (m.z + m.w);
    ssq += (m.x * m.x + m.y * m.y) + (m.z * m.z + m.w * m.w);
  }
  for (int off = 32; off; off >>= 1) sum += __shfl_xor(sum, off, 64);
  for (int off = 32; off; off >>= 1) ssq += __shfl_xor(ssq, off, 64);
  if (lane == 0) { rA[wid] = sum; rB[wid] = ssq; }
  __syncthreads();
  sum = ((rA[0] + rA[1]) + (rA[2] + rA[3]));  // fixed order: deterministic
  ssq = ((rB[0] + rB[1]) + (rB[2] + rB[3]));
  const float mean = sum / (float)NPTS;
  const float var  = (ssq - (float)NPTS * mean * mean) / (float)(NPTS - 1);
  const float neg_thr = -0.5f * sqrtf(fmaxf(var, 0.0f));

  float ksum = 0.0f, kcnt = 0.0f;
#pragma unroll
  for (int k = 0; k < PGRP; ++k) {
    float4 t = mreg[k];
    if (t.x - mean > neg_thr) { ksum += t.x; kcnt += 1.0f; }
    if (t.y - mean > neg_thr) { ksum += t.y; kcnt += 1.0f; }
    if (t.z - mean > neg_thr) { ksum += t.z; kcnt += 1.0f; }
    if (t.w - mean > neg_thr) { ksum += t.w; kcnt += 1.0f; }
  }
  for (int off = 32; off; off >>= 1) ksum += __shfl_xor(ksum, off, 64);
  for (int off = 32; off; off >>= 1) kcnt += __shfl_xor(kcnt, off, 64);
  if (lane == 0) { rC[wid] = ksum; rD[wid] = kcnt; }
  __syncthreads();

  if (threadIdx.x == 0) {
    ksum = ((rC[0] + rC[1]) + (rC[2] + rC[3]));
    kcnt = ((rD[0] + rD[1]) + (rD[2] + rD[3]));
    __hip_atomic_store(&res[w], ksum / kcnt, __ATOMIC_RELAXED,
                       __HIP_MEMORY_SCOPE_AGENT);
    __threadfence();  // release: res[w] visible before ticket bump
    unsigned int old = atomicAdd(ticket, 1u);  // device-scope by default
    if (old == 15u) {
      __threadfence();  // acquire: all res[] writes visible
      float tot = 0.0f;
      for (int i = 0; i < 16; ++i) {  // fixed order: bit-deterministic
        tot += __hip_atomic_load(&res[i], __ATOMIC_RELAXED,
                                 __HIP_MEMORY_SCOPE_AGENT);
      }
      out[0] = tot / (float)BATCH;
    }
  }
}

extern "C" void kernel_launch(void* const* d_in, const int* in_sizes, int n_in,
                              void* d_out, int out_size, void* d_ws, size_t ws_size,
                              hipStream_t stream) {
  const float* x = (const float*)d_in[0];
  const float* y = (const float*)d_in[1];
  float* out = (float*)d_out;
  float* partial = (float*)d_ws;                       // 16*2*8*4096*4B = 4 MB
  float* res = partial + (size_t)NCHUNK * 2 * BATCH * NPTS;  // 16 floats
  unsigned int* ticket = (unsigned int*)(res + 16);

  dim3 g1(PGRP, BATCH, 2 * NCHUNK);
  dmin_kernel<<<g1, BLK, 0, stream>>>(x, y, partial, ticket);
  finalize_kernel<<<16, BLK, 0, stream>>>(partial, res, ticket, out);
}

// Round 9
// 32.822 us; speedup vs baseline: 4.4748x; 1.0349x over previous
//
#include <hip/hip_runtime.h>

#define NPTS 4096
#define BATCH 8
#define BLK 256
#define PPT 8                        // p-points per thread
#define NPB (BLK * PPT)              // 2048 p-points per block
#define MCH 256                      // q-points staged in LDS per block
#define NCHUNK (NPTS / MCH)          // 16
#define PGRP (NPTS / NPB)            // 2
#define FREG (NPTS / 4 / BLK)        // 4 float4 per finalize thread

// ---------------------------------------------------------------------------
// Kernel 1: partial min over one q-chunk. grid = (2, 8, 32) = 512 blocks.
// LDS holds (-2qx,-2qy,-2qz,|q|^2); |p|^2 folded out: d' = |q|^2 - 2 p.q
// (3 FMA/pair). PPT=8 so each ds_read_b128 feeds 8 pairs -> LDS pipe
// (~10 us/CU) drops below the VALU floor (~12 us). Also zeroes the finalize
// ticket (stream order guarantees this precedes dispatch 2).
// ---------------------------------------------------------------------------
__global__ __launch_bounds__(BLK, 2) void dmin_kernel(
    const float* __restrict__ X, const float* __restrict__ Y,
    float* __restrict__ partial, unsigned int* __restrict__ ticket) {
  if (blockIdx.x == 0 && blockIdx.y == 0 && blockIdx.z == 0 &&
      threadIdx.x == 0) {
    __hip_atomic_store(ticket, 0u, __ATOMIC_RELAXED, __HIP_MEMORY_SCOPE_AGENT);
  }

  const int pg    = blockIdx.x;
  const int b     = blockIdx.y;
  const int chunk = blockIdx.z & (NCHUNK - 1);
  const int dir   = blockIdx.z >> 4;
  const float* pts = dir ? Y : X;  // set we compute mins for
  const float* oth = dir ? X : Y;  // set we min over

  __shared__ float4 s[MCH];  // 4 KB
  const float* othb = oth + ((size_t)b * NPTS + (size_t)chunk * MCH) * 3;
  {
    const int i = threadIdx.x;  // MCH == BLK: one q per thread
    float qx = othb[3 * i], qy = othb[3 * i + 1], qz = othb[3 * i + 2];
    s[i] = make_float4(-2.f * qx, -2.f * qy, -2.f * qz,
                       qx * qx + qy * qy + qz * qz);
  }
  __syncthreads();

  const int n0 = pg * NPB + threadIdx.x * PPT;  // 8 consecutive p-points
  // 24 consecutive floats, 96B-aligned -> 6 float4 loads
  const float4* pv4 = (const float4*)(pts + ((size_t)b * NPTS + n0) * 3);
  const float4 A = pv4[0], B = pv4[1], C = pv4[2];
  const float4 D = pv4[3], E = pv4[4], F = pv4[5];
  float px[PPT], py[PPT], pz[PPT];
  px[0] = A.x; py[0] = A.y; pz[0] = A.z;
  px[1] = A.w; py[1] = B.x; pz[1] = B.y;
  px[2] = B.z; py[2] = B.w; pz[2] = C.x;
  px[3] = C.y; py[3] = C.z; pz[3] = C.w;
  px[4] = D.x; py[4] = D.y; pz[4] = D.z;
  px[5] = D.w; py[5] = E.x; pz[5] = E.y;
  px[6] = E.z; py[6] = E.w; pz[6] = F.x;
  px[7] = F.y; py[7] = F.z; pz[7] = F.w;

  float acc[2 * PPT];
#pragma unroll
  for (int i = 0; i < 2 * PPT; ++i) acc[i] = 3.4e38f;

#pragma unroll 2
  for (int m = 0; m < MCH; m += 4) {
    float4 q0 = s[m + 0], q1 = s[m + 1], q2 = s[m + 2], q3 = s[m + 3];
#pragma unroll
    for (int pp = 0; pp < PPT; ++pp) {
      float d0 = fmaf(px[pp], q0.x, fmaf(py[pp], q0.y, fmaf(pz[pp], q0.z, q0.w)));
      float d1 = fmaf(px[pp], q1.x, fmaf(py[pp], q1.y, fmaf(pz[pp], q1.z, q1.w)));
      float d2 = fmaf(px[pp], q2.x, fmaf(py[pp], q2.y, fmaf(pz[pp], q2.z, q2.w)));
      float d3 = fmaf(px[pp], q3.x, fmaf(py[pp], q3.y, fmaf(pz[pp], q3.z, q3.w)));
      acc[2 * pp]     = fminf(fminf(acc[2 * pp], d0), d1);      // v_min3
      acc[2 * pp + 1] = fminf(fminf(acc[2 * pp + 1], d2), d3);  // v_min3
    }
  }

  float r[PPT];
#pragma unroll
  for (int pp = 0; pp < PPT; ++pp) {
    float c = px[pp] * px[pp] + py[pp] * py[pp] + pz[pp] * pz[pp];
    r[pp] = fminf(acc[2 * pp], acc[2 * pp + 1]) + c;
  }
  float* dst = &partial[(((size_t)chunk * 2 + dir) * BATCH + b) * NPTS + n0];
  ((float4*)dst)[0] = make_float4(r[0], r[1], r[2], r[3]);
  ((float4*)dst)[1] = make_float4(r[4], r[5], r[6], r[7]);
}

// ---------------------------------------------------------------------------
// Kernel 2: 16 blocks, block w = (dir,b). 16-way chunk-min in registers,
// fused sum/ssq (one-pass ddof=1 var), strict mask (v-mean > -0.5*std),
// fixed-order reductions -> res[w]. Last block (ticket) sums res[0..15] in
// fixed index order -> out[0]. No memset, no spin-wait, bit-deterministic.
// ---------------------------------------------------------------------------
__global__ __launch_bounds__(BLK) void finalize_kernel(
    const float* __restrict__ partial, float* __restrict__ res,
    unsigned int* __restrict__ ticket, float* __restrict__ out) {
  const int w    = blockIdx.x;   // dir*8 + b
  const int dir  = w >> 3;
  const int b    = w & 7;
  const int wid  = threadIdx.x >> 6;
  const int lane = threadIdx.x & 63;

  __shared__ float rA[4], rB[4], rC[4], rD[4];

  const float4* pv = (const float4*)partial;
  const size_t vbase = ((size_t)dir * BATCH + b) * (NPTS / 4);
  const size_t cstr  = (size_t)2 * BATCH * (NPTS / 4);

  float4 mreg[FREG];  // this thread's 4 minned float4s, kept in registers
  float sum = 0.0f, ssq = 0.0f;
#pragma unroll
  for (int k = 0; k < FREG; ++k) {
    const int i = threadIdx.x + k * BLK;
    float4 m = pv[vbase + i];
#pragma unroll
    for (int c = 1; c < NCHUNK; ++c) {
      float4 t = pv[vbase + (size_t)c * cstr + i];
      m.x = fminf(m.x, t.x); m.y = fminf(m.y, t.y);
      m.z = fminf(m.z, t.z); m.w = fminf(m.w, t.w);
    }
    mreg[k] = m;
    sum += (m.x + m.y) + (m.z + m.w);
    ssq += (m.x * m.x + m.y * m.y) + (m.z * m.z + m.w * m.w);
  }
  for (int off = 32; off; off >>= 1) sum += __shfl_xor(sum, off, 64);
  for (int off = 32; off; off >>= 1) ssq += __shfl_xor(ssq, off, 64);
  if (lane == 0) { rA[wid] = sum; rB[wid] = ssq; }
  __syncthreads();
  sum = ((rA[0] + rA[1]) + (rA[2] + rA[3]));  // fixed order: deterministic
  ssq = ((rB[0] + rB[1]) + (rB[2] + rB[3]));
  const float mean = sum / (float)NPTS;
  const float var  = (ssq - (float)NPTS * mean * mean) / (float)(NPTS - 1);
  const float neg_thr = -0.5f * sqrtf(fmaxf(var, 0.0f));

  float ksum = 0.0f, kcnt = 0.0f;
#pragma unroll
  for (int k = 0; k < FREG; ++k) {
    float4 t = mreg[k];
    if (t.x - mean > neg_thr) { ksum += t.x; kcnt += 1.0f; }
    if (t.y - mean > neg_thr) { ksum += t.y; kcnt += 1.0f; }
    if (t.z - mean > neg_thr) { ksum += t.z; kcnt += 1.0f; }
    if (t.w - mean > neg_thr) { ksum += t.w; kcnt += 1.0f; }
  }
  for (int off = 32; off; off >>= 1) ksum += __shfl_xor(ksum, off, 64);
  for (int off = 32; off; off >>= 1) kcnt += __shfl_xor(kcnt, off, 64);
  if (lane == 0) { rC[wid] = ksum; rD[wid] = kcnt; }
  __syncthreads();

  if (threadIdx.x == 0) {
    ksum = ((rC[0] + rC[1]) + (rC[2] + rC[3]));
    kcnt = ((rD[0] + rD[1]) + (rD[2] + rD[3]));
    __hip_atomic_store(&res[w], ksum / kcnt, __ATOMIC_RELAXED,
                       __HIP_MEMORY_SCOPE_AGENT);
    __threadfence();  // release: res[w] visible before ticket bump
    unsigned int old = atomicAdd(ticket, 1u);  // device-scope by default
    if (old == 15u) {
      __threadfence();  // acquire: all res[] writes visible
      float tot = 0.0f;
      for (int i = 0; i < 16; ++i) {  // fixed order: bit-deterministic
        tot += __hip_atomic_load(&res[i], __ATOMIC_RELAXED,
                                 __HIP_MEMORY_SCOPE_AGENT);
      }
      out[0] = tot / (float)BATCH;
    }
  }
}

extern "C" void kernel_launch(void* const* d_in, const int* in_sizes, int n_in,
                              void* d_out, int out_size, void* d_ws, size_t ws_size,
                              hipStream_t stream) {
  const float* x = (const float*)d_in[0];
  const float* y = (const float*)d_in[1];
  float* out = (float*)d_out;
  float* partial = (float*)d_ws;                       // 16*2*8*4096*4B = 4 MB
  float* res = partial + (size_t)NCHUNK * 2 * BATCH * NPTS;  // 16 floats
  unsigned int* ticket = (unsigned int*)(res + 16);

  dim3 g1(PGRP, BATCH, 2 * NCHUNK);
  dmin_kernel<<<g1, BLK, 0, stream>>>(x, y, partial, ticket);
  finalize_kernel<<<16, BLK, 0, stream>>>(partial, res, ticket, out);
}